// Round 1
// 207.654 us; speedup vs baseline: 1.0706x; 1.0706x over previous
//
#include <hip/hip_runtime.h>

// FindInstancePeaks: fused conv backbone + global peak finding.
// crops (128,192,192,1) f32 -> conv1 3x3 s2 SAME (1->32) + relu
//                          -> conv2 3x3 s1 SAME (32->17) = cms (128,96,96,17)
// -> per (b,n): argmax over 96x96, quarter-pixel sign refine, *2, NaN<0.2.
//
// R9: two changes vs R8, both attacking VALU starvation (VALUBusy 56%,
// Occupancy 28.7% == exact signature of the 1152-on-1024-slot dispatch tail):
//  (1) retile to 12 tiles of 24x48 per image (3 px/thread), grid 1536.
//      1536 = 1024 + 512 at 4 blocks/CU: the tail round runs 2 blocks on
//      EVERY CU instead of 1 block on HALF the CUs. (Also exactly 2 rounds
//      if occupancy ever drops to 3 blocks/CU.)
//  (2) conv2 accumulates 17 channels as 8x float2 + 1 scalar so the inner
//      loop emits v_pk_fma_f32 (packed fp32 = the only path to 157 TF;
//      scalar v_fmac_f32 caps at 78.6 TF). Weight pairs are contiguous in
//      W2 (uniform s_loads); h is broadcast. Same FMAs, same order ->
//      bit-identical output. acc regs: 17x3 = 51 (was 68) -- pays for the
//      pack without breaking the (256,4) 128-reg unified budget.

#define NCH 17
#define C1 32
#define TW 24           // tile width  (4 cols)
#define TH 32           // tile height (3 rows)
#define HT_W 26         // h cols needed (TW+2)
#define HT_H 34         // h rows needed (TH+2)
#define HSTR 28         // s_h col stride
#define IN_W 53         // input patch cols: 2*HT_W+1
#define IN_H 69         // input patch rows: 2*HT_H+1
#define CG 4            // conv1 channels per group
#define NG 8            // groups

typedef float v2f __attribute__((ext_vector_type(2)));

__device__ __forceinline__ unsigned long long pack_key(float v, unsigned flat) {
    unsigned ub = __float_as_uint(v);
    ub = (ub & 0x80000000u) ? ~ub : (ub | 0x80000000u);   // monotone float->uint
    return ((unsigned long long)ub << 32) | (unsigned)(~flat); // ~flat: ties -> lowest idx
}

__global__ __launch_bounds__(256, 4) void conv_peaks_kernel(
    const float* __restrict__ crops, const float* __restrict__ W1g,
    const float* __restrict__ b1g, const float* __restrict__ W2g,
    const float* __restrict__ b2g, unsigned long long* __restrict__ peaks) {
    __shared__ float s_in[IN_H * IN_W];                      // 14628 B
    __shared__ __align__(16) float s_h[CG * HT_H * HSTR];    // 15232 B

    const int t = threadIdx.x;
    const int b = blockIdx.y;
    const int ty0 = (blockIdx.x >> 2) * TH;   // 0,32,64
    const int tx0 = (blockIdx.x & 3) * TW;    // 0,24,48,72
    const int iy0 = 2 * ty0 - 2;
    const int ix0 = 2 * tx0 - 2;
    const float* cb = crops + b * 192 * 192;

    // --- stage input patch (zero-padded at image borders) ---
    for (int p = t; p < IN_H * IN_W; p += 256) {
        int r = p / IN_W, cc = p - r * IN_W;
        int iy = iy0 + r, ix = ix0 + cc;
        float v = 0.f;
        if (iy >= 0 && ix >= 0 && iy < 192 && ix < 192) v = cb[iy * 192 + ix];
        s_in[p] = v;
    }

    // thread -> 3 contiguous pixels: row ly, cols lx0..lx0+2
    const int ly = t >> 3;            // 0..31
    const int lx0 = (t & 7) * 3;      // 0,3,...,21
    v2f acc2[8][3];                   // channel pairs (2m, 2m+1)
    float acc1[3];                    // channel 16
#pragma unroll
    for (int m = 0; m < 8; ++m)
#pragma unroll
        for (int p = 0; p < 3; ++p) acc2[m][p] = (v2f)(0.f);
#pragma unroll
    for (int p = 0; p < 3; ++p) acc1[p] = 0.f;

#pragma unroll 1
    for (int g = 0; g < NG; ++g) {
        __syncthreads();   // prev conv2 reads / staging done before overwrite

        // conv1 + relu for this group's 4 channels
        for (int p = t; p < HT_H * HT_W; p += 256) {
            int r = p / HT_W, cc = p - r * HT_W;
            int hy = ty0 - 1 + r, hx = tx0 - 1 + cc;
            bool valid = (hy >= 0) && (hy < 96) && (hx >= 0) && (hx < 96);
            float in9[9];
#pragma unroll
            for (int q = 0; q < 9; ++q)
                in9[q] = s_in[(2 * r + q / 3) * IN_W + (2 * cc + q % 3)];
#pragma unroll
            for (int cl = 0; cl < CG; ++cl) {
                int c = g * CG + cl;
                float a = b1g[c];
#pragma unroll
                for (int q = 0; q < 9; ++q) a = fmaf(in9[q], W1g[q * C1 + c], a);
                a = valid ? fmaxf(a, 0.f) : 0.f;
                s_h[cl * (HT_H * HSTR) + r * HSTR + cc] = a;
            }
        }
        __syncthreads();

        // conv2 partial: per cl, load 3 h-rows x 5 floats once (LDS), read
        // W2 via uniform s_load (SGPRs), then register-only packed FMAs:
        // per tap: 3 px x (8 v_pk_fma_f32 + 1 fma) on channel pairs.
#pragma unroll 1
        for (int cl = 0; cl < CG; ++cl) {
            float hrow[3][5];
            const float* hp = s_h + cl * (HT_H * HSTR) + ly * HSTR + lx0;
#pragma unroll
            for (int r = 0; r < 3; ++r)
#pragma unroll
                for (int j = 0; j < 5; ++j) hrow[r][j] = hp[r * HSTR + j];
            const int c = g * CG + cl;
#pragma unroll
            for (int k = 0; k < 9; ++k) {
                const int ky = k / 3, kx = k - ky * 3;
                const float* wb = W2g + (k * C1 + c) * NCH;  // uniform -> s_load
                float w[NCH];
#pragma unroll
                for (int n = 0; n < NCH; ++n) w[n] = wb[n];
                v2f wp[8];
#pragma unroll
                for (int m = 0; m < 8; ++m) wp[m] = (v2f){w[2 * m], w[2 * m + 1]};
#pragma unroll
                for (int p = 0; p < 3; ++p) {
                    const float h = hrow[ky][kx + p];
                    const v2f hh = {h, h};
#pragma unroll
                    for (int m = 0; m < 8; ++m)
                        acc2[m][p] = __builtin_elementwise_fma(hh, wp[m], acc2[m][p]);
                    acc1[p] = fmaf(h, w[16], acc1[p]);
                }
            }
        }
    }

    // --- per-channel argmax: in-thread max over 3 px, then wave reduce ---
    const int yg = ty0 + ly, xg = tx0 + lx0;
    const int lane = t & 63;
#pragma unroll
    for (int n = 0; n < NCH; ++n) {
        const float bb = b2g[n];
        float v_[3];
#pragma unroll
        for (int p = 0; p < 3; ++p)
            v_[p] = ((n < 16) ? acc2[n >> 1][p][n & 1] : acc1[p]) + bb;
        unsigned long long pk = pack_key(v_[0], (unsigned)(yg * 96 + xg));
#pragma unroll
        for (int p = 1; p < 3; ++p) {
            unsigned long long o = pack_key(v_[p], (unsigned)(yg * 96 + xg + p));
            if (o > pk) pk = o;
        }
#pragma unroll
        for (int off = 32; off; off >>= 1) {
            unsigned long long o = __shfl_down(pk, off, 64);
            if (o > pk) pk = o;
        }
        if (lane == 0) atomicMax(&peaks[b * NCH + n], pk);
    }
}

// One 64-lane wave per (b,n): decode peak, recompute 4 clipped neighbor cms
// values (b2 cancels in the sign differences), emit (x,y,val).
// 16 lanes per neighbor, 2 channels per lane. The 7x7 crops patch for the
// neighbor is channel-independent: hoisted, 49 broadcast loads, then the
// whole channel loop is load-free FMAs (W1/W2 loads are per-lane c,
// coalesced across the 16-lane group).
__global__ __launch_bounds__(64) void refine_kernel(
    const float* __restrict__ crops, const float* __restrict__ W1g,
    const float* __restrict__ b1g, const float* __restrict__ W2g,
    const unsigned long long* __restrict__ peaks, float* __restrict__ out) {
    const int bn = blockIdx.x;          // 0..128*17-1
    const int b = bn / NCH, n = bn % NCH;
    const int lane = threadIdx.x;

    unsigned long long pk = peaks[bn];
    unsigned key = (unsigned)(pk >> 32);
    unsigned fbits = (key & 0x80000000u) ? (key ^ 0x80000000u) : ~key;
    float val = __uint_as_float(fbits);
    int flat = (int)(~(unsigned)(pk & 0xffffffffu));
    int yi = flat / 96, xi = flat - yi * 96;

    // neighbor j: 0:(yi,xi+1) 1:(yi,xi-1) 2:(yi+1,xi) 3:(yi-1,xi), clipped
    const int j = lane >> 4;
    int yy = yi + ((j == 2) ? 1 : 0) - ((j == 3) ? 1 : 0);
    int xx = xi + ((j == 0) ? 1 : 0) - ((j == 1) ? 1 : 0);
    yy = min(max(yy, 0), 95);
    xx = min(max(xx, 0), 95);

    // hoist 7x7 crops patch: rows 2yy-2..2yy+4, cols 2xx-2..2xx+4
    const float* cb = crops + b * 192 * 192;
    float pat[7][7];
#pragma unroll
    for (int r = 0; r < 7; ++r) {
        int iy = 2 * yy - 2 + r;
#pragma unroll
        for (int s = 0; s < 7; ++s) {
            int ix = 2 * xx - 2 + s;
            pat[r][s] = (iy >= 0 && iy < 192 && ix >= 0 && ix < 192)
                            ? cb[iy * 192 + ix] : 0.f;
        }
    }

    float part = 0.f;
#pragma unroll
    for (int ci = 0; ci < 2; ++ci) {
        const int c = (lane & 15) + ci * 16;
        const float bias = b1g[c];
        float w1[9];
#pragma unroll
        for (int q = 0; q < 9; ++q) w1[q] = W1g[q * C1 + c];
#pragma unroll
        for (int dy = 0; dy < 3; ++dy) {
#pragma unroll
            for (int dx = 0; dx < 3; ++dx) {
                int hy = yy - 1 + dy, hx = xx - 1 + dx;
                if (hy >= 0 && hy < 96 && hx >= 0 && hx < 96) {
                    float a = bias;
#pragma unroll
                    for (int qy = 0; qy < 3; ++qy)
#pragma unroll
                        for (int qx = 0; qx < 3; ++qx)
                            a = fmaf(pat[2 * dy + qy][2 * dx + qx],
                                     w1[qy * 3 + qx], a);
                    float hval = fmaxf(a, 0.f);
                    part = fmaf(hval, W2g[((dy * 3 + dx) * C1 + c) * NCH + n], part);
                }
            }
        }
    }
    // sum the 16 lanes of each neighbor group
    for (int off = 8; off; off >>= 1) part += __shfl_down(part, off, 16);
    float g0 = __shfl(part, 0, 64);
    float g1 = __shfl(part, 16, 64);
    float g2 = __shfl(part, 32, 64);
    float g3 = __shfl(part, 48, 64);

    if (lane == 0) {
        float d0 = g0 - g1, d1 = g2 - g3;
        float sx = (d0 > 0.f) ? 1.f : ((d0 < 0.f) ? -1.f : 0.f);
        float sy = (d1 > 0.f) ? 1.f : ((d1 < 0.f) ? -1.f : 0.f);
        float px = ((float)xi + 0.25f * sx) * 2.f;
        float py = ((float)yi + 0.25f * sy) * 2.f;
        if (!(val >= 0.2f)) {
            px = __int_as_float(0x7fc00000);
            py = __int_as_float(0x7fc00000);
        }
        out[bn * 3 + 0] = px;
        out[bn * 3 + 1] = py;
        out[bn * 3 + 2] = val;
    }
}

extern "C" void kernel_launch(void* const* d_in, const int* in_sizes, int n_in,
                              void* d_out, int out_size, void* d_ws, size_t ws_size,
                              hipStream_t stream) {
    const float* crops = (const float*)d_in[0];
    const float* W1 = (const float*)d_in[1];
    const float* b1 = (const float*)d_in[2];
    const float* W2 = (const float*)d_in[3];
    const float* b2 = (const float*)d_in[4];
    float* out = (float*)d_out;
    unsigned long long* peaks = (unsigned long long*)d_ws;

    hipMemsetAsync(d_ws, 0, 128 * NCH * sizeof(unsigned long long), stream);

    dim3 gridB(12, 128);  // 4x3 tiles of 24x48 over 96x96, per image
    conv_peaks_kernel<<<gridB, 256, 0, stream>>>(crops, W1, b1, W2, b2, peaks);
    refine_kernel<<<128 * NCH, 64, 0, stream>>>(crops, W1, b1, W2, peaks, out);
}